// Round 2
// baseline (2376.479 us; speedup 1.0000x reference)
//
#include <hip/hip_runtime.h>
#include <cstddef>

#define HW 128
#define NPIX 16384  // 128*128

typedef short short8 __attribute__((ext_vector_type(8)));
typedef short short4v __attribute__((ext_vector_type(4)));
typedef float floatx4 __attribute__((ext_vector_type(4)));

static __device__ __forceinline__ unsigned short f2bf(float f) {
    unsigned int u = __float_as_uint(f);
    u += 0x7fffu + ((u >> 16) & 1u);
    return (unsigned short)(u >> 16);
}
static __device__ __forceinline__ float bf2f(unsigned short s) {
    return __uint_as_float(((unsigned int)s) << 16);
}

// wt[t][co][ci] = bf16(w[co][ci][kh][kw]), t = kh*3+kw. Tiny; runs every call.
__global__ __launch_bounds__(256) void prep_weights(
    const float* __restrict__ w, unsigned short* __restrict__ wt, int co_total)
{
    const int idx = blockIdx.x * 256 + threadIdx.x;
    const int total = co_total * 2304;
    if (idx >= total) return;
    const int per_t = co_total * 256;
    const int t = idx / per_t;
    const int rem = idx - t * per_t;
    const int co = rem >> 8;
    const int ci = rem & 255;
    wt[idx] = f2bf(w[(co * 256 + ci) * 9 + t]);
}

// NCHW fp32 -> NHWC bf16 tiled transpose. Tile 64px x 64ci per block.
// Phase1: wave reads 64 consecutive px of one ci (coalesced 256B), LDS [px][ci].
// Phase2: write 64 consecutive ci of one px (coalesced 128B).
// LDS pad 66: write addr stride 33 dwords -> bank = px%32, 2-way (free).
__global__ __launch_bounds__(256) void prep_transpose(
    const float* __restrict__ in, unsigned short* __restrict__ out)
{
    __shared__ unsigned short t[64][66];
    const int px0 = blockIdx.x * 64;
    const int ci0 = blockIdx.y * 64;
    const int b = blockIdx.z;
    const int lane = threadIdx.x & 63;
    const int wv = threadIdx.x >> 6;
    const float* src = in + ((size_t)b * 256 + ci0) * NPIX + px0;
#pragma unroll
    for (int k = 0; k < 16; ++k) {
        const int cl = wv + k * 4;
        t[lane][cl] = f2bf(src[(size_t)cl * NPIX + lane]);
    }
    __syncthreads();
    unsigned short* dst = out + ((size_t)b * NPIX + px0) * 256 + ci0;
#pragma unroll
    for (int k = 0; k < 16; ++k) {
        const int pl = wv + k * 4;
        dst[(size_t)pl * 256 + lane] = t[pl][lane];
    }
}

// Implicit-GEMM conv3x3 (pad=1) + BN(affine) + ReLU via bf16 MFMA.
// Tap decomposition: O[co][p] = sum_t W_t[co][ci] * X[ci][p_shift(t)].
// Block: 256 thr = 4 waves; output tile = 64 co x (16x16 px). Wave w: all 64 co
// of this co-block x 4 tile rows (orow0 = w*4). Per chunk: 32 ci staged in LDS
// pixel-major [324 px][32 ci] bf16 so b-frags are single ds_read_b128.
// Input modes (uniform branch):
//   in1_b != nullptr: NHWC bf16 (row len = cin1 for in1_b, 256-cin1 for in2_b)
//     -> staging is 1 dwordx4 load + 1 ds_write_b128 per iter (no f2bf).
//   else: fp32 NCHW pair (in1_f/in2_f), 8 scalar loads + f2bf (fallback for K3
//     when workspace is too small for NHWC copies).
// Output modes: out_b != nullptr -> NHWC bf16 (short4 stores); else NCHW fp32.
__global__ __launch_bounds__(256, 2) void conv3x3_mfma(
    const unsigned short* __restrict__ in1_b, const unsigned short* __restrict__ in2_b,
    const float* __restrict__ in1_f, const float* __restrict__ in2_f, int cin1,
    const unsigned short* __restrict__ wt,
    const float* __restrict__ g, const float* __restrict__ bb,
    float* __restrict__ out_f, unsigned short* __restrict__ out_b, int co_total)
{
    __shared__ unsigned short xs[324 * 32];  // 20736 B
    const int tid = threadIdx.x;
    const int lane = tid & 63;
    const int wv = tid >> 6;        // wave 0..3
    const int px = lane & 15;       // MFMA m/n lane index
    const int quad = lane >> 4;     // MFMA k-quad
    const int cob = blockIdx.x;     // co-block of 64
    const int tile = blockIdx.y;    // 64 spatial tiles of 16x16
    const int b = blockIdx.z;
    const int ty0 = (tile >> 3) * 16, tx0 = (tile & 7) * 16;
    const int cin2 = 256 - cin1;
    const int orow0 = wv * 4;       // this wave's 4 tile rows

    floatx4 acc[4][4];
#pragma unroll
    for (int mg = 0; mg < 4; ++mg)
#pragma unroll
        for (int ng = 0; ng < 4; ++ng) acc[mg][ng] = (floatx4){0.f, 0.f, 0.f, 0.f};

    for (int ck = 0; ck < 8; ++ck) {
        const int ci0 = ck * 32;
        if (in1_b) {
            // ---- NHWC bf16 staging: vector loads, channel-contiguous
            for (int it = tid; it < 1296; it += 256) {
                const int q = it & 3;
                const int pix = it >> 2;
                const int r = pix / 18;
                const int c = pix - r * 18;
                const int gh = ty0 + r - 1, gw = tx0 + c - 1;
                short8 sv;
                if (gh >= 0 && gh < HW && gw >= 0 && gw < HW) {
                    const int cig = ci0 + q * 8;
                    const size_t off = (size_t)b * NPIX + gh * HW + gw;
                    sv = (cig < cin1)
                        ? *(const short8*)(in1_b + off * cin1 + cig)
                        : *(const short8*)(in2_b + off * cin2 + (cig - cin1));
                } else {
                    sv = (short8){0, 0, 0, 0, 0, 0, 0, 0};
                }
                *(short8*)&xs[pix * 32 + q * 8] = sv;
            }
        } else {
            // ---- fp32 NCHW staging (fallback): transpose-by-gather + f2bf
            for (int it = tid; it < 1296; it += 256) {
                const int q = it & 3;
                const int pix = it >> 2;
                const int r = pix / 18;
                const int c = pix - r * 18;
                const int gh = ty0 + r - 1, gw = tx0 + c - 1;
                short8 sv;
                if (gh >= 0 && gh < HW && gw >= 0 && gw < HW) {
                    const int off = gh * HW + gw;
#pragma unroll
                    for (int i = 0; i < 8; ++i) {
                        const int cig = ci0 + q * 8 + i;
                        const float* src = (cig < cin1)
                            ? in1_f + ((size_t)b * cin1 + cig) * NPIX
                            : in2_f + ((size_t)b * cin2 + (cig - cin1)) * NPIX;
                        sv[i] = (short)f2bf(src[off]);
                    }
                } else {
#pragma unroll
                    for (int i = 0; i < 8; ++i) sv[i] = 0;
                }
                *(short8*)&xs[pix * 32 + q * 8] = sv;
            }
        }
        __syncthreads();

        // ---- 9 taps x 16 MFMA, a/b frags reused 4x each
#pragma unroll
        for (int kh = 0; kh < 3; ++kh) {
#pragma unroll
            for (int kw = 0; kw < 3; ++kw) {
                const int t = kh * 3 + kw;
                short8 a[4], bf[4];
#pragma unroll
                for (int mg = 0; mg < 4; ++mg) {
                    const int co = cob * 64 + mg * 16 + px;
                    a[mg] = *(const short8*)(wt + (((size_t)(t * co_total + co)) << 8)
                                             + ci0 + quad * 8);
                }
#pragma unroll
                for (int ng = 0; ng < 4; ++ng) {
                    const int row = orow0 + ng + kh;
                    bf[ng] = *(const short8*)&xs[(row * 18 + px + kw) * 32 + quad * 8];
                }
#pragma unroll
                for (int mg = 0; mg < 4; ++mg)
#pragma unroll
                    for (int ng = 0; ng < 4; ++ng)
                        acc[mg][ng] = __builtin_amdgcn_mfma_f32_16x16x32_bf16(
                            a[mg], bf[ng], acc[mg][ng], 0, 0, 0);
            }
        }
        __syncthreads();
    }

    // ---- epilogue: BN affine + ReLU
#pragma unroll
    for (int mg = 0; mg < 4; ++mg) {
#pragma unroll
        for (int ng = 0; ng < 4; ++ng) {
            const int h = ty0 + orow0 + ng;
            const int wcol = tx0 + px;
            const int cobase = cob * 64 + mg * 16 + quad * 4;
            if (out_b) {
                short4v sv;
#pragma unroll
                for (int r = 0; r < 4; ++r) {
                    float v = acc[mg][ng][r] * g[cobase + r] + bb[cobase + r];
                    v = v > 0.f ? v : 0.f;
                    sv[r] = (short)f2bf(v);
                }
                *(short4v*)(out_b + ((size_t)b * NPIX + h * HW + wcol) * co_total
                            + cobase) = sv;
            } else {
#pragma unroll
                for (int r = 0; r < 4; ++r) {
                    float v = acc[mg][ng][r] * g[cobase + r] + bb[cobase + r];
                    v = v > 0.f ? v : 0.f;
                    out_f[((size_t)b * co_total + cobase + r) * NPIX + h * HW + wcol] = v;
                }
            }
        }
    }
}

// One wave per (head, window). lane = query pixel. y1/y2 are NHWC bf16.
// Optionally also writes NHWC bf16 copies (y1o/y2o) for K3's fast staging.
__global__ __launch_bounds__(64) void win_attn(
    const unsigned short* __restrict__ y1, const unsigned short* __restrict__ y2,
    const float* __restrict__ wq1, const float* __restrict__ bq1,
    const float* __restrict__ wk1, const float* __restrict__ bk1,
    const float* __restrict__ wv1, const float* __restrict__ bv1,
    const float* __restrict__ wq2, const float* __restrict__ bq2,
    const float* __restrict__ wk2, const float* __restrict__ bk2,
    const float* __restrict__ wv2, const float* __restrict__ bv2,
    float* __restrict__ x1i, float* __restrict__ x2i,
    unsigned short* __restrict__ y1o, unsigned short* __restrict__ y2o)
{
    const int n = blockIdx.x;        // head
    const int wid = blockIdx.y;      // window
    const int b = wid >> 8;
    const int wi = wid & 255;
    const int hy = wi >> 4, wx = wi & 15;
    const int p = threadIdx.x;
    const int iy = p >> 3, ix = p & 7;
    const int h = hy * 8 + iy, ww = wx * 8 + ix;
    const size_t pix = (size_t)h * HW + ww;

    const unsigned short* x1p = y1 + ((size_t)b * NPIX + pix) * 128;
    const unsigned short* x2p = y2 + ((size_t)b * NPIX + pix) * 128;

    float q1[4], q2[4], k1r[8], k2r[8], v1r[16], v2r[16];
#pragma unroll
    for (int d = 0; d < 4; ++d) { q1[d] = bq1[n * 4 + d]; q2[d] = bq2[n * 4 + d]; }
#pragma unroll
    for (int e = 0; e < 8; ++e) { k1r[e] = bk1[n * 8 + e]; k2r[e] = bk2[n * 8 + e]; }
#pragma unroll
    for (int f = 0; f < 16; ++f) { v1r[f] = bv1[n * 16 + f]; v2r[f] = bv2[n * 16 + f]; }

    for (int cg = 0; cg < 16; ++cg) {
        const short8 a1 = *(const short8*)(x1p + cg * 8);
        const short8 a2 = *(const short8*)(x2p + cg * 8);
#pragma unroll
        for (int j = 0; j < 8; ++j) {
            const int c = cg * 8 + j;
            const float xv1 = bf2f((unsigned short)a1[j]);
            const float xv2 = bf2f((unsigned short)a2[j]);
#pragma unroll
            for (int d = 0; d < 4; ++d) {
                q1[d] = fmaf(xv1, wq1[(n * 4 + d) * 128 + c], q1[d]);
                q2[d] = fmaf(xv2, wq2[(n * 4 + d) * 128 + c], q2[d]);
            }
#pragma unroll
            for (int e = 0; e < 8; ++e) {
                k1r[e] = fmaf(xv1, wk1[(n * 8 + e) * 128 + c], k1r[e]);
                k2r[e] = fmaf(xv2, wk2[(n * 8 + e) * 128 + c], k2r[e]);
            }
#pragma unroll
            for (int f = 0; f < 16; ++f) {
                v1r[f] = fmaf(xv1, wv1[(n * 16 + f) * 128 + c], v1r[f]);
                v2r[f] = fmaf(xv2, wv2[(n * 16 + f) * 128 + c], v2r[f]);
            }
        }
    }

    __shared__ __align__(16) float ks1[64][12];
    __shared__ __align__(16) float ks2[64][12];
    __shared__ __align__(16) float vs1[64][20];
    __shared__ __align__(16) float vs2[64][20];
#pragma unroll
    for (int e = 0; e < 8; ++e) { ks1[p][e] = k1r[e]; ks2[p][e] = k2r[e]; }
#pragma unroll
    for (int f = 0; f < 16; ++f) { vs1[p][f] = v1r[f]; vs2[p][f] = v2r[f]; }
    __syncthreads();

    float m = -1e30f;
    for (int kk = 0; kk < 64; ++kk) {
        float s1 = 0.f, s2 = 0.f;
#pragma unroll
        for (int d = 0; d < 4; ++d) {
            s1 = fmaf(q1[d], ks1[kk][d], s1);
            s2 = fmaf(q1[d], ks2[kk][d], s2);
        }
#pragma unroll
        for (int d = 0; d < 4; ++d) {
            s1 = fmaf(q2[d], ks1[kk][4 + d], s1);
            s2 = fmaf(q2[d], ks2[kk][4 + d], s2);
        }
        m = fmaxf(m, fabsf(s1 - s2));
    }

    float o1[16], o2[16];
#pragma unroll
    for (int f = 0; f < 16; ++f) { o1[f] = 0.f; o2[f] = 0.f; }
    float sum = 0.f;
    for (int kk = 0; kk < 64; ++kk) {
        float s1 = 0.f, s2 = 0.f;
#pragma unroll
        for (int d = 0; d < 4; ++d) {
            s1 = fmaf(q1[d], ks1[kk][d], s1);
            s2 = fmaf(q1[d], ks2[kk][d], s2);
        }
#pragma unroll
        for (int d = 0; d < 4; ++d) {
            s1 = fmaf(q2[d], ks1[kk][4 + d], s1);
            s2 = fmaf(q2[d], ks2[kk][4 + d], s2);
        }
        const float e = __expf(fabsf(s1 - s2) - m);
        sum += e;
#pragma unroll
        for (int f = 0; f < 16; ++f) {
            o1[f] = fmaf(e, vs1[kk][f], o1[f]);
            o2[f] = fmaf(e, vs2[kk][f], o2[f]);
        }
    }
    const float inv = 1.f / sum;
    float* o1p = x1i + ((size_t)b * 128 + n * 16) * NPIX + pix;
    float* o2p = x2i + ((size_t)b * 128 + n * 16) * NPIX + pix;
#pragma unroll
    for (int f = 0; f < 16; ++f) {
        o1p[(size_t)f * NPIX] = o1[f] * inv;
        o2p[(size_t)f * NPIX] = o2[f] * inv;
    }
    if (y1o) {
        short8 s1a, s1b, s2a, s2b;
#pragma unroll
        for (int f = 0; f < 8; ++f) {
            s1a[f] = (short)f2bf(o1[f] * inv);
            s1b[f] = (short)f2bf(o1[8 + f] * inv);
            s2a[f] = (short)f2bf(o2[f] * inv);
            s2b[f] = (short)f2bf(o2[8 + f] * inv);
        }
        unsigned short* p1 = y1o + ((size_t)b * NPIX + pix) * 128 + n * 16;
        unsigned short* p2 = y2o + ((size_t)b * NPIX + pix) * 128 + n * 16;
        *(short8*)p1 = s1a;
        *(short8*)(p1 + 8) = s1b;
        *(short8*)p2 = s2a;
        *(short8*)(p2 + 8) = s2b;
    }
}

extern "C" void kernel_launch(void* const* d_in, const int* in_sizes, int n_in,
                              void* d_out, int out_size, void* d_ws, size_t ws_size,
                              hipStream_t stream) {
    const float* x1    = (const float*)d_in[0];
    const float* x2    = (const float*)d_in[1];
    const float* w_ic1 = (const float*)d_in[2];
    const float* g_ic1 = (const float*)d_in[3];
    const float* b_ic1 = (const float*)d_in[4];
    const float* w_ic2 = (const float*)d_in[5];
    const float* g_ic2 = (const float*)d_in[6];
    const float* b_ic2 = (const float*)d_in[7];
    const float* wq1   = (const float*)d_in[8];
    const float* bq1   = (const float*)d_in[9];
    const float* wk1   = (const float*)d_in[10];
    const float* bk1   = (const float*)d_in[11];
    const float* wv1   = (const float*)d_in[12];
    const float* bv1   = (const float*)d_in[13];
    const float* wq2   = (const float*)d_in[14];
    const float* bq2   = (const float*)d_in[15];
    const float* wk2   = (const float*)d_in[16];
    const float* bk2   = (const float*)d_in[17];
    const float* wv2   = (const float*)d_in[18];
    const float* bv2   = (const float*)d_in[19];
    const float* w_cat = (const float*)d_in[20];
    const float* g_cat = (const float*)d_in[21];
    const float* b_cat = (const float*)d_in[22];

    float* out = (float*)d_out;
    // d_out scratch map (shorts, inside the x_cat fp32 region [0, 33.5M floats)):
    //   xT  [0, 33554432)          : NHWC bf16 of ONE input (reused x1 then x2)
    //   y1  [33554432, 50331648)   : conv1 out, NHWC bf16
    //   y2  [50331648, 67108864)   : conv2 out, NHWC bf16  (exactly fills region)
    // K3 overwrites the whole region last; its inputs live in x1i/x2i or ws.
    unsigned short* xT = (unsigned short*)d_out;
    unsigned short* y1 = xT + 33554432;
    unsigned short* y2 = y1 + 16777216;
    float* x1i  = out + 33554432;
    float* x2i  = out + 50331648;
    float* xcat = out;

    // d_ws: bf16 weights [tap][co][ci]; then (if room) NHWC bf16 copies of
    // x1i/x2i written by win_attn for K3's vectorized staging.
    unsigned short* wt_ic1 = (unsigned short*)d_ws;
    unsigned short* wt_ic2 = wt_ic1 + 294912;   // 128*256*9
    unsigned short* wt_cat = wt_ic2 + 294912;   // 256*256*9 = 589824
    const size_t WS_NEED = 2359296ull + 2ull * 33554432ull;  // weights + y1o + y2o
    const bool big_ws = ws_size >= WS_NEED;
    unsigned short* y1o = big_ws ? wt_cat + 589824 : nullptr;
    unsigned short* y2o = big_ws ? y1o + 16777216 : nullptr;

    prep_weights<<<dim3(1152), dim3(256), 0, stream>>>(w_ic1, wt_ic1, 128);
    prep_weights<<<dim3(1152), dim3(256), 0, stream>>>(w_ic2, wt_ic2, 128);
    prep_weights<<<dim3(2304), dim3(256), 0, stream>>>(w_cat, wt_cat, 256);

    // K1a: x1 -> NHWC bf16 -> conv -> y1 (NHWC bf16)
    prep_transpose<<<dim3(256, 4, 8), dim3(256), 0, stream>>>(x1, xT);
    conv3x3_mfma<<<dim3(2, 64, 8), dim3(256), 0, stream>>>(
        xT, xT, nullptr, nullptr, 256, wt_ic1, g_ic1, b_ic1, nullptr, y1, 128);
    // K1b: x2 (xT reused; stream order serializes with conv above)
    prep_transpose<<<dim3(256, 4, 8), dim3(256), 0, stream>>>(x2, xT);
    conv3x3_mfma<<<dim3(2, 64, 8), dim3(256), 0, stream>>>(
        xT, xT, nullptr, nullptr, 256, wt_ic2, g_ic2, b_ic2, nullptr, y2, 128);

    // K2: fused QKV + window attention (NHWC reads; fp32 planar outputs +
    // optional NHWC bf16 copies for K3)
    win_attn<<<dim3(8, 2048), dim3(64), 0, stream>>>(y1, y2,
        wq1, bq1, wk1, bk1, wv1, bv1,
        wq2, bq2, wk2, bk2, wv2, bv2,
        x1i, x2i, y1o, y2o);

    // K3: cat conv (128+128 -> 256), fp32 NCHW out
    if (big_ws) {
        conv3x3_mfma<<<dim3(4, 64, 8), dim3(256), 0, stream>>>(
            y1o, y2o, nullptr, nullptr, 128, wt_cat, g_cat, b_cat, xcat, nullptr, 256);
    } else {
        conv3x3_mfma<<<dim3(4, 64, 8), dim3(256), 0, stream>>>(
            nullptr, nullptr, x1i, x2i, 128, wt_cat, g_cat, b_cat, xcat, nullptr, 256);
    }
}